// Round 13
// baseline (255.238 us; speedup 1.0000x reference)
//
#include <hip/hip_runtime.h>
#include <stdint.h>

#define B_ 16
#define H_ 64
#define W_ 64
#define D_ 64
#define C_ 16
#define K_ 5
#define N_ 4096
#define NC_ 16         // attention n-chunks
#define CS_ 256        // chunk size = N_/NC_
#define EPS 1e-5f

typedef __attribute__((ext_vector_type(8))) short bf16x8;
typedef __attribute__((ext_vector_type(4))) float f32x4;

__device__ __forceinline__ float wsum64(float v){
  #pragma unroll
  for(int o=1;o<64;o<<=1) v += __shfl_xor(v,o,64);
  return v;
}
__device__ __forceinline__ float wmax64(float v){
  #pragma unroll
  for(int o=1;o<64;o<<=1) v = fmaxf(v, __shfl_xor(v,o,64));
  return v;
}
__device__ __forceinline__ float wmin64(float v){
  #pragma unroll
  for(int o=1;o<64;o<<=1) v = fminf(v, __shfl_xor(v,o,64));
  return v;
}
__device__ __forceinline__ uint16_t f2bf(float f){
  uint32_t u = __float_as_uint(f);
  u += 0x7fffu + ((u>>16)&1u);
  return (uint16_t)(u>>16);
}

// k_pre: fgpos (0-4) + folded biases (5) + fvb/wgx/wgy/gscal/out_slot-zero (6)
// + wqpT/wrpT/wvT/wmT (7-70) + gw (71-166) + slot init (167-186)
__global__ __launch_bounds__(256) void k_pre(
    const float* __restrict__ mask, const float* __restrict__ noise,
    const float* __restrict__ mu, const float* __restrict__ lsg,
    const float* __restrict__ wm, const float* __restrict__ bm, const float* __restrict__ lnkb,
    const float* __restrict__ wk, const float* __restrict__ wv, const float* __restrict__ lnfb,
    const float* __restrict__ wq, const float* __restrict__ lnqg, const float* __restrict__ lnqb,
    const float* __restrict__ wres, const float* __restrict__ bres,
    const float* __restrict__ lnrg, const float* __restrict__ lnrb,
    const float* __restrict__ wih, const float* __restrict__ whh,
    const float* __restrict__ wg, const float* __restrict__ bg,
    float* __restrict__ ws_fg, float* __restrict__ out_fg,
    float* __restrict__ bm2, float* __restrict__ fkb, float* __restrict__ fvb,
    float* __restrict__ qb, float* __restrict__ br2,
    float* __restrict__ wgx, float* __restrict__ wgy, float* __restrict__ gscal,
    float* __restrict__ wqpT, float* __restrict__ wrpT,
    float* __restrict__ wvT, float* __restrict__ wmT,
    float* __restrict__ gw, float* __restrict__ slot, float* __restrict__ out_slot){
  int bid=blockIdx.x, tid=threadIdx.x;
  if(bid<5){
    int k=bid;
    float sm=0.f, sx=0.f, sy=0.f;
    for(int p=tid; p<H_*W_; p+=256){
      int i=p>>6, j=p&63;
      float m = mask[k*H_*W_ + p];
      float x = -1.f + (2.f/63.f)*j;
      float y = -1.f + (2.f/63.f)*i;
      sm+=m; sx+=m*x; sy+=m*y;
    }
    __shared__ float r0[4], r1[4], r2[4];
    int wid=tid>>6, lane=tid&63;
    sm=wsum64(sm); sx=wsum64(sx); sy=wsum64(sy);
    if(lane==0){ r0[wid]=sm; r1[wid]=sx; r2[wid]=sy; }
    __syncthreads();
    if(tid==0){
      float tm=r0[0]+r0[1]+r0[2]+r0[3];
      float tx=r1[0]+r1[1]+r1[2]+r1[3];
      float ty=r2[0]+r2[1]+r2[2]+r2[3];
      float px = tx/(tm+1e-5f), py = ty/(tm+1e-5f);
      ws_fg[k*2+0]=px; ws_fg[k*2+1]=py;
      for(int b=0;b<B_;b++){ out_fg[(b*K_+k)*2+0]=px; out_fg[(b*K_+k)*2+1]=py; }
    }
  } else if(bid==5){
    int sel=tid>>6, o=tid&63; float s=0.f;
    if(sel==0){ s=bm[o]; for(int d=0;d<64;d++) s+=lnkb[d]*wm[o*64+d]; bm2[o]=s; }
    else if(sel==1){ for(int d=0;d<64;d++) s+=lnqb[d]*wq[o*64+d]; qb[o]=0.125f*s; }
    else if(sel==2){ for(int d=0;d<64;d++) s+=lnrb[d]*wres[o*64+d]; br2[o]=s+bres[o]; }
    else { for(int d=0;d<64;d++) s+=lnfb[d]*wk[o*64+d]; fkb[o]=s; }
  } else if(bid==6){
    int wv4=tid>>6, l=tid&63;
    if(wv4==0){ float s=0.f; for(int d=0;d<64;d++) s+=lnfb[d]*wv[l*64+d]; fvb[l]=s; }
    else if(wv4==1){
      float4 w4 = *(const float4*)(wg + l*4);
      wgx[l]=w4.x-w4.z; wgy[l]=w4.y-w4.w;
    } else if(wv4==2){
      float4 w4 = *(const float4*)(wg + l*4);
      float wx=w4.x-w4.z, wy=w4.y-w4.w, bl=bg[l];
      float t;
      t=wsum64(wx);    if(l==0) gscal[0]=t*(1.f/64.f);
      t=wsum64(wy);    if(l==0) gscal[1]=t*(1.f/64.f);
      t=wsum64(bl);    if(l==0) gscal[2]=t*(1.f/64.f);
      t=wsum64(wx*wx); if(l==0) gscal[3]=t*(1.f/64.f);
      t=wsum64(wy*wy); if(l==0) gscal[4]=t*(1.f/64.f);
      t=wsum64(wx*wy); if(l==0) gscal[5]=t*(2.f/64.f);
      t=wsum64(wx*bl); if(l==0) gscal[6]=t*(2.f/64.f);
      t=wsum64(wy*bl); if(l==0) gscal[7]=t*(2.f/64.f);
      t=wsum64(bl*bl); if(l==0) gscal[8]=t*(1.f/64.f);
    } else {
      for(int j=l;j<B_*K_*16;j+=64){ int bk2=j>>4, cc2=j&15; out_slot[bk2*80+64+cc2]=0.f; }
    }
  } else if(bid<71){
    int i=(bid-7)*256+tid;           // < 16384
    int a=i>>12, r=i&4095, d=r>>6, o=r&63;
    if(a==0)      wqpT[r]=0.125f*lnqg[d]*wq[o*64+d];
    else if(a==1) wrpT[r]=lnrg[d]*wres[o*64+d];
    else if(a==2) wvT[r]=wv[o*64+d];
    else          wmT[r]=wm[o*64+d];
  } else if(bid<167){
    int i=(bid-71)*256+tid;          // < 24576
    int g6=i>>12, r=i&4095, d=r>>6, o=r&63;
    float v = (g6<3)? wih[(g6*64+o)*64+d] : whh[((g6-3)*64+o)*64+d];
    gw[g6*4096 + d*64 + o] = v;
  } else {
    int i=(bid-167)*256+tid;
    if(i<B_*K_*D_){ int d=i&63; slot[i]=mu[d]+expf(lsg[d])*noise[i]; }
  }
}

// feat LN -> A (bf16); transient MFMA fk/fv rows -> per-row stat float4s; color LN.
__global__ __launch_bounds__(256) void k_featln(const float* __restrict__ feat,
    const float* __restrict__ wk, const float* __restrict__ wv, const float* __restrict__ gf,
    const float* __restrict__ fkb, const float* __restrict__ fvb,
    const float* __restrict__ wgx, const float* __restrict__ wgy, const float* __restrict__ bg,
    const float* __restrict__ fc, const float* __restrict__ gc, const float* __restrict__ bc,
    uint16_t* __restrict__ Aout, float4* __restrict__ kstat, float4* __restrict__ vstat,
    float* __restrict__ fcn){
  int tid=threadIdx.x, wid=tid>>6, lane=tid&63;
  int q=lane>>4, c=lane&15;
  size_t row = (size_t)blockIdx.x*64 + wid*16 + c;
  const float* xp = feat + row*64;
  float x[16];
  *(float4*)&x[0]  = *(const float4*)(xp + q*8);
  *(float4*)&x[4]  = *(const float4*)(xp + q*8 + 4);
  *(float4*)&x[8]  = *(const float4*)(xp + 32 + q*8);
  *(float4*)&x[12] = *(const float4*)(xp + 36 + q*8);
  float s=0.f;
  #pragma unroll
  for(int i=0;i<16;i++) s+=x[i];
  s += __shfl_xor(s,16,64); s += __shfl_xor(s,32,64);
  float mean = s*(1.f/64.f);
  float v=0.f;
  #pragma unroll
  for(int i=0;i<16;i++){ float d=x[i]-mean; v+=d*d; }
  v += __shfl_xor(v,16,64); v += __shfl_xor(v,32,64);
  float rs = rsqrtf(v*(1.f/64.f)+EPS);
  float gl[16];
  *(float4*)&gl[0]  = *(const float4*)(gf + q*8);
  *(float4*)&gl[4]  = *(const float4*)(gf + q*8 + 4);
  *(float4*)&gl[8]  = *(const float4*)(gf + 32 + q*8);
  *(float4*)&gl[12] = *(const float4*)(gf + 36 + q*8);
  bf16x8 A0, A1;
  #pragma unroll
  for(int j=0;j<8;j++){
    A0[j] = (short)f2bf((x[j]  -mean)*rs);
    A1[j] = (short)f2bf((x[8+j]-mean)*rs);
  }
  *(bf16x8*)(Aout + row*64 + q*8) = A0;
  *(bf16x8*)(Aout + row*64 + 32 + q*8) = A1;
  float wgxl[4][4], wgyl[4][4], bgl[4][4];
  #pragma unroll
  for(int ot=0;ot<4;ot++){
    *(float4*)&wgxl[ot][0] = *(const float4*)(wgx + ot*16 + q*4);
    *(float4*)&wgyl[ot][0] = *(const float4*)(wgy + ot*16 + q*4);
    *(float4*)&bgl[ot][0]  = *(const float4*)(bg + ot*16 + q*4);
  }
  #pragma unroll
  for(int mat=0;mat<2;mat++){
    const float* w = mat? wv : wk;
    const float* fb = mat? fvb : fkb;
    float ss=0.f, s2=0.f, dx=0.f, dy=0.f, db=0.f;
    #pragma unroll
    for(int ot=0; ot<4; ot++){
      const float* wp = w + (size_t)(ot*16+c)*64 + q*8;
      bf16x8 W0, W1;
      #pragma unroll
      for(int j=0;j<8;j++){ W0[j]=(short)f2bf(wp[j]*gl[j]); W1[j]=(short)f2bf(wp[32+j]*gl[8+j]); }
      float4 bq = *(const float4*)(fb + ot*16 + q*4);
      f32x4 acc = {bq.x,bq.y,bq.z,bq.w};
      acc = __builtin_amdgcn_mfma_f32_16x16x32_bf16(W0, A0, acc, 0,0,0);
      acc = __builtin_amdgcn_mfma_f32_16x16x32_bf16(W1, A1, acc, 0,0,0);
      #pragma unroll
      for(int r=0;r<4;r++){
        float a=acc[r];
        ss+=a; s2+=a*a;
        dx = fmaf(a, wgxl[ot][r], dx);
        dy = fmaf(a, wgyl[ot][r], dy);
        db = fmaf(a, bgl[ot][r], db);
      }
    }
    ss += __shfl_xor(ss,16,64); ss += __shfl_xor(ss,32,64);
    s2 += __shfl_xor(s2,16,64); s2 += __shfl_xor(s2,32,64);
    dx += __shfl_xor(dx,16,64); dx += __shfl_xor(dx,32,64);
    dy += __shfl_xor(dy,16,64); dy += __shfl_xor(dy,32,64);
    db += __shfl_xor(db,16,64); db += __shfl_xor(db,32,64);
    if(lane<16){
      size_t row2 = (size_t)blockIdx.x*64 + wid*16 + lane;
      float4 st = { ss*(1.f/64.f), s2*(1.f/64.f)+db*(1.f/32.f), dx*(1.f/32.f), dy*(1.f/32.f) };
      (mat? vstat : kstat)[row2] = st;
    }
  }
  int r16=tid>>4, cc=tid&15;
  #pragma unroll
  for(int i=0;i<4;i++){
    size_t row2 = (size_t)blockIdx.x*64 + i*16 + r16;
    float xv = fc[row2*16+cc];
    float sc=xv;
    #pragma unroll
    for(int o=1;o<16;o<<=1) sc += __shfl_xor(sc,o,16);
    float m2 = sc*(1.f/16.f);
    float df = xv-m2;
    float v2 = df*df;
    #pragma unroll
    for(int o=1;o<16;o<<=1) v2 += __shfl_xor(v2,o,16);
    fcn[row2*16+cc] = df*rsqrtf(v2*(1.f/16.f)+EPS)*gc[cc] + bc[cc];
  }
}

struct AttnP {
  const uint16_t* Aw; const float4* kst; const float4* vst;
  const float* gw; const float* bih; const float* bhh;
  const float* wrpT; const float* br2; const float* wqpT; const float* qb;
  const float* wm; const float* wk; const float* lnfg; const float* lnkg;
  const float* fkb; const float* bm2; const float* fvb;
  const float* wvT; const float* wmT;
  const float* wgx; const float* wgy; const float* bg;
  const float* gs; const float* fg; float* lgt;
};

// Slot-amortized attention with fused block-parallel preamble (all 5 slots).
// Grid (NC_, B_). Preamble redundant per chunk-block; qs/cst stay in LDS.
template<bool GRU, bool FINAL>
__global__ __launch_bounds__(256) void k_attn(AttnP P,
    const float* __restrict__ sprev, float* __restrict__ scur,
    const float* __restrict__ prt_in, const float* __restrict__ psc_in,
    const float* __restrict__ red_in,
    float* __restrict__ red_out, float* __restrict__ prt_out, float* __restrict__ psc_out){
  __shared__ uint32_t As_[CS_*32];       // 32KB: 256 rows x 64 bf16
  __shared__ float dps[5][CS_+4];        // dots/weights; qp stash in preamble
  __shared__ float scratch[4][64][15];   // MV5 partials / pw alias
  __shared__ float vvs[5][64], vh[5][64], qsl[5][64];
  __shared__ float scal5[5][4];
  __shared__ float cstl[5][5];
  __shared__ float fgl[5][2];
  __shared__ float rm[4], rn[4];
  __shared__ float rsc[4][5];
  int chunk=blockIdx.x, b=blockIdx.y;
  int tid=threadIdx.x, wid=tid>>6, lane=tid&63;
  int c=lane&15, q=lane>>4;
  int o=lane, qq=wid;
  float mwgx=P.gs[0], mwgy=P.gs[1], mbg=P.gs[2];
  float g1=P.gs[3], g2=P.gs[4], g3=P.gs[5], g4=P.gs[6], g5=P.gs[7], g6=P.gs[8];

  // stage A chunk -> LDS (used in accumulation) + fg
  const uint4* Ag = (const uint4*)(P.Aw + ((size_t)b*N_ + chunk*CS_)*64);
  #pragma unroll
  for(int jj=0;jj<8;jj++){
    int f = jj*256 + tid;
    *(uint4*)(As_ + f*4) = Ag[f];
  }
  if(tid<10) fgl[tid>>1][tid&1] = P.fg[tid];
  // per-thread row stats
  int nrow = chunk*CS_ + tid;
  float4 st = P.kst[(size_t)b*N_ + nrow];
  float4 sv;
  if(!FINAL) sv = P.vst[(size_t)b*N_ + nrow];
  float gx = -1.f + (2.f/63.f)*(nrow&63);
  float gy = -1.f + (2.f/63.f)*(nrow>>6);

  #define MV5(W) { float p0=0.f,p1=0.f,p2=0.f,p3=0.f,p4=0.f; \
    _Pragma("unroll") \
    for(int dd=0;dd<16;dd++){ int d_=qq*16+dd; float w_=(W)[d_*64+o]; \
      p0=fmaf(vvs[0][d_],w_,p0); p1=fmaf(vvs[1][d_],w_,p1); \
      p2=fmaf(vvs[2][d_],w_,p2); p3=fmaf(vvs[3][d_],w_,p3); \
      p4=fmaf(vvs[4][d_],w_,p4); } \
    scratch[qq][o][0]=p0; scratch[qq][o][1]=p1; scratch[qq][o][2]=p2; \
    scratch[qq][o][3]=p3; scratch[qq][o][4]=p4; } __syncthreads();
  #define SUM5(k) (scratch[0][lane][k]+scratch[1][lane][k]+scratch[2][lane][k]+scratch[3][lane][k])

  // ===== preamble =====
  if(GRU){
    // merge chunk partials: wave w handles slot w (round 0), wave 0 slot 4 (round 1)
    #pragma unroll
    for(int rd=0;rd<2;rd++){
      int k = (rd==0)? wid : (wid==0? 4 : -1);
      if(k>=0 && k<5){
        int bk=b*K_+k;
        float mred[NC_], sred[NC_];
        float M=-1e30f;
        #pragma unroll
        for(int cc=0;cc<NC_;cc++){
          const float* rp = red_in + ((size_t)bk*NC_+cc)*4;
          mred[cc]=rp[0]; sred[cc]=rp[1];
          M=fmaxf(M,mred[cc]);
        }
        float S=0.f;
        #pragma unroll
        for(int cc=0;cc<NC_;cc++){ mred[cc]=__expf(mred[cc]-M); S=fmaf(sred[cc],mred[cc],S); }
        float invS=1.f/S;
        float sA=0.f, As=0.f, Ax=0.f, Ay=0.f, Am=0.f;
        #pragma unroll
        for(int cc=0;cc<NC_;cc++){
          float lam = mred[cc]*invS;
          sA = fmaf(lam, prt_in[((size_t)bk*NC_+cc)*64+lane], sA);
          const float* pp = psc_in + ((size_t)bk*NC_+cc)*4;
          As=fmaf(lam,pp[0],As); Ax=fmaf(lam,pp[1],Ax);
          Ay=fmaf(lam,pp[2],Ay); Am=fmaf(lam,pp[3],Am);
        }
        vvs[k][lane] = P.lnfg[lane]*sA;
        if(lane==0){ scal5[k][0]=As; scal5[k][1]=Ax; scal5[k][2]=Ay; scal5[k][3]=Am; }
      }
    }
    __syncthreads();
    MV5(P.wvT);
    if(wid==0){
      #pragma unroll
      for(int k=0;k<5;k++){
        float As=scal5[k][0],Ax=scal5[k][1],Ay=scal5[k][2],Am=scal5[k][3];
        float fvs = SUM5(k) + P.fvb[lane]*As;
        float zs = fvs + Ax*P.wgx[lane] + Ay*P.wgy[lane] + As*P.bg[lane] - Am;
        vvs[k][lane] = P.lnkg[lane]*zs;
      }
    }
    __syncthreads();
    MV5(P.wmT);
    if(wid==0){
      #pragma unroll
      for(int k=0;k<5;k++){
        vh[k][lane] = sprev[(b*K_+k)*64+lane];
        vvs[k][lane] = SUM5(k) + P.bm2[lane];
      }
    }
    __syncthreads();
    // gate stage A (x-gates r,z,n)
    {
      float p[15];
      #pragma unroll
      for(int i=0;i<15;i++) p[i]=0.f;
      #pragma unroll
      for(int dd=0;dd<16;dd++){
        int d_=qq*16+dd;
        float w0=P.gw[d_*64+o], w1=P.gw[4096+d_*64+o], w2=P.gw[8192+d_*64+o];
        #pragma unroll
        for(int k=0;k<5;k++){
          float xd=vvs[k][d_];
          p[k]=fmaf(xd,w0,p[k]); p[5+k]=fmaf(xd,w1,p[5+k]); p[10+k]=fmaf(xd,w2,p[10+k]);
        }
      }
      #pragma unroll
      for(int i=0;i<15;i++) scratch[qq][o][i]=p[i];
    }
    __syncthreads();
    float gA[15];
    if(wid==0){
      #pragma unroll
      for(int i=0;i<15;i++) gA[i]=scratch[0][lane][i]+scratch[1][lane][i]+scratch[2][lane][i]+scratch[3][lane][i];
    }
    __syncthreads();
    // gate stage B (h-gates)
    {
      float p[15];
      #pragma unroll
      for(int i=0;i<15;i++) p[i]=0.f;
      #pragma unroll
      for(int dd=0;dd<16;dd++){
        int d_=qq*16+dd;
        float w0=P.gw[12288+d_*64+o], w1=P.gw[16384+d_*64+o], w2=P.gw[20480+d_*64+o];
        #pragma unroll
        for(int k=0;k<5;k++){
          float hd=vh[k][d_];
          p[k]=fmaf(hd,w0,p[k]); p[5+k]=fmaf(hd,w1,p[5+k]); p[10+k]=fmaf(hd,w2,p[10+k]);
        }
      }
      #pragma unroll
      for(int i=0;i<15;i++) scratch[qq][o][i]=p[i];
    }
    __syncthreads();
    if(wid==0){
      float gB[15];
      #pragma unroll
      for(int i=0;i<15;i++) gB[i]=scratch[0][lane][i]+scratch[1][lane][i]+scratch[2][lane][i]+scratch[3][lane][i];
      float b0=P.bih[lane], b1=P.bih[64+lane], b2=P.bih[128+lane];
      float h0=P.bhh[lane], h1=P.bhh[64+lane], h2=P.bhh[128+lane];
      #pragma unroll
      for(int k=0;k<5;k++){
        float gir=gA[k]+b0, giz=gA[5+k]+b1, gin=gA[10+k]+b2;
        float ghr=gB[k]+h0, ghz=gB[5+k]+h1, ghn=gB[10+k]+h2;
        float r=1.f/(1.f+__expf(-(gir+ghr)));
        float z=1.f/(1.f+__expf(-(giz+ghz)));
        float nn=tanhf(gin+r*ghn);
        float hp=vh[k][lane];
        float sp=(1.f-z)*nn+z*hp;
        float m=wsum64(sp)*(1.f/64.f); float df=sp-m;
        float var=wsum64(df*df)*(1.f/64.f);
        vvs[k][lane]=df*rsqrtf(var+EPS);
      }
    }
    __syncthreads();
    MV5(P.wrpT);
    if(wid==0){
      #pragma unroll
      for(int k=0;k<5;k++){
        float cur = SUM5(k) + P.br2[lane] + vh[k][lane];
        if(chunk==0) scur[(b*K_+k)*64+lane]=cur;
        float m=wsum64(cur)*(1.f/64.f); float df=cur-m;
        float var=wsum64(df*df)*(1.f/64.f);
        vvs[k][lane]=df*rsqrtf(var+EPS);
      }
    }
  } else {
    if(wid==0){
      #pragma unroll
      for(int k=0;k<5;k++){
        float cur = sprev[(b*K_+k)*64+lane];
        float m=wsum64(cur)*(1.f/64.f); float df=cur-m;
        float var=wsum64(df*df)*(1.f/64.f);
        vvs[k][lane]=df*rsqrtf(var+EPS);
      }
    }
  }
  __syncthreads();
  MV5(P.wqpT);
  if(wid==0){
    #pragma unroll
    for(int k=0;k<5;k++){ float qv=SUM5(k)+P.qb[lane]; vh[k][lane]=qv; vvs[k][lane]=qv; }
  }
  __syncthreads();
  MV5(P.wm);
  if(wid==0){
    #pragma unroll
    for(int k=0;k<5;k++){ float qp=SUM5(k)*P.lnkg[lane]; dps[k][lane]=qp; vvs[k][lane]=qp; }
  }
  __syncthreads();
  MV5(P.wk);
  if(wid==0){
    #pragma unroll
    for(int k=0;k<5;k++){
      qsl[k][lane]=SUM5(k)*P.lnfg[lane];
      float qp=dps[k][lane], qv=vh[k][lane];
      float s1 = wsum64(qp);
      float c1 = wsum64(qp*P.wgx[lane]);
      float c2 = wsum64(qp*P.wgy[lane]);
      float c3 = wsum64(qp*(P.bg[lane]+P.fkb[lane]));
      float c4c = wsum64(qv*P.bm2[lane]);
      if(lane==0){
        cstl[k][0]=c1-s1*mwgx; cstl[k][1]=c2-s1*mwgy; cstl[k][2]=c3-s1*mbg;
        cstl[k][3]=s1; cstl[k][4]=c4c;
      }
    }
  }
  __syncthreads();
  #undef MV5
  #undef SUM5

  // ===== phase 1: MFMA dots (A from global, aligned; q from LDS) =====
  {
    bf16x8 QF0={0,0,0,0,0,0,0,0}, QF1={0,0,0,0,0,0,0,0};
    if(c<5){
      #pragma unroll
      for(int j=0;j<8;j++){
        QF0[j] = (short)f2bf(qsl[c][q*8+j]);
        QF1[j] = (short)f2bf(qsl[c][32+q*8+j]);
      }
    }
    const uint16_t* Abase = P.Aw + ((size_t)b*N_ + chunk*CS_)*64;
    #pragma unroll
    for(int it2=0;it2<4;it2++){
      int tile = wid*64 + it2*16;
      const uint16_t* rp = Abase + (size_t)(tile+c)*64;
      bf16x8 BF0 = *(const bf16x8*)(rp + q*8);
      bf16x8 BF1 = *(const bf16x8*)(rp + 32 + q*8);
      f32x4 acc = {0.f,0.f,0.f,0.f};
      acc = __builtin_amdgcn_mfma_f32_16x16x32_bf16(QF0, BF0, acc, 0,0,0);
      acc = __builtin_amdgcn_mfma_f32_16x16x32_bf16(QF1, BF1, acc, 0,0,0);
      #pragma unroll
      for(int r=0;r<4;r++){
        int s = q*4+r;
        if(s<5) dps[s][tile+c]=acc[r];
      }
    }
  }
  __syncthreads();

  // ===== phase 2: per-(row,k) logits + chunk-local softmax =====
  #pragma unroll
  for(int k=0;k<5;k++){
    float rx = gx - fgl[k][0], ry = gy - fgl[k][1];
    float CX=cstl[k][0], CY=cstl[k][1], C0=cstl[k][2], S1=cstl[k][3], C4=cstl[k][4];
    float quad = g1*rx*rx + g2*ry*ry + g3*rx*ry + g4*rx + g5*ry + g6;
    float mu = st.x + rx*mwgx + ry*mwgy + mbg;
    float var = st.y + rx*st.z + ry*st.w + quad - mu*mu;
    float rsn = rsqrtf(var+EPS);
    float l = rsn*(dps[k][tid] + rx*CX + ry*CY + C0 - S1*st.x) + C4;
    float wmx = wmax64(l);
    if(lane==0) rm[wid]=wmx;
    if(FINAL){ float mn=wmin64(l); if(lane==0) rn[wid]=mn; }
    __syncthreads();
    float m_c = fmaxf(fmaxf(rm[0],rm[1]),fmaxf(rm[2],rm[3]));
    float e = __expf(l-m_c);
    float scq=e, As2=0.f, Ax2=0.f, Ay2=0.f, Am2=0.f, w_=0.f;
    if(!FINAL){
      float muV = sv.x + rx*mwgx + ry*mwgy + mbg;
      float varV = sv.y + rx*sv.z + ry*sv.w + quad - muV*muV;
      float rsv_ = rsqrtf(varV+EPS);
      w_ = e*rsv_;
      As2=w_; Ax2=w_*rx; Ay2=w_*ry; Am2=w_*muV;
    } else {
      P.lgt[(size_t)(b*K_+k)*N_ + nrow] = l;
    }
    scq=wsum64(scq);
    if(!FINAL){ As2=wsum64(As2); Ax2=wsum64(Ax2); Ay2=wsum64(Ay2); Am2=wsum64(Am2); }
    if(lane==0){ rsc[wid][0]=scq; rsc[wid][1]=As2; rsc[wid][2]=Ax2; rsc[wid][3]=Ay2; rsc[wid][4]=Am2; }
    __syncthreads();
    if(tid==0){
      size_t idx = ((size_t)(b*K_+k)*NC_+chunk)*4;
      red_out[idx+0]=m_c;
      red_out[idx+1]=rsc[0][0]+rsc[1][0]+rsc[2][0]+rsc[3][0];
      if(FINAL) red_out[idx+2]=fminf(fminf(rn[0],rn[1]),fminf(rn[2],rn[3]));
      if(!FINAL){
        psc_out[idx+0]=rsc[0][1]+rsc[1][1]+rsc[2][1]+rsc[3][1];
        psc_out[idx+1]=rsc[0][2]+rsc[1][2]+rsc[2][2]+rsc[3][2];
        psc_out[idx+2]=rsc[0][3]+rsc[1][3]+rsc[2][3]+rsc[3][3];
        psc_out[idx+3]=rsc[0][4]+rsc[1][4]+rsc[2][4]+rsc[3][4];
      }
    }
    if(!FINAL) dps[k][tid]=w_;
  }

  // ===== accumulation: part[k][ch] = sum_row w_k[row]*A[row][ch] =====
  if(!FINAL){
    __syncthreads();
    const uint16_t* Au = (const uint16_t*)As_;
    float a[5]={0.f,0.f,0.f,0.f,0.f};
    for(int r64=0;r64<64;r64++){
      int row = wid*64 + r64;
      float av = __uint_as_float(((uint32_t)Au[row*64+lane])<<16);
      #pragma unroll
      for(int k=0;k<5;k++) a[k]=fmaf(dps[k][row], av, a[k]);
    }
    #pragma unroll
    for(int k=0;k<5;k++) scratch[wid][lane][k]=a[k];
    __syncthreads();
    if(tid<64){
      #pragma unroll
      for(int k=0;k<5;k++){
        float s2 = scratch[0][tid][k]+scratch[1][tid][k]+scratch[2][tid][k]+scratch[3][tid][k];
        prt_out[((size_t)(b*K_+k)*NC_+chunk)*64 + tid] = s2;
      }
    }
  }
}

// fin: p from global stats; out_attn; color partial atomicAdd; slot write (chunk 0)
__global__ __launch_bounds__(256) void k_fin(const float* __restrict__ lgt,
    const float* __restrict__ red, const float* __restrict__ featc,
    const float* __restrict__ sl1, float* __restrict__ out_slot,
    float* __restrict__ out_attn){
  __shared__ float psp[CS_];
  __shared__ float pcz[4][16];
  int chunk=blockIdx.x, bk=blockIdx.y, b=bk/K_;
  int tid=threadIdx.x, wid=tid>>6, lane=tid&63, sub=lane>>4, c4=lane&15;
  const float* rp = red + (size_t)bk*NC_*4;
  float M=-1e30f;
  #pragma unroll
  for(int i=0;i<NC_;i++) M = fmaxf(M, rp[i*4]);
  float S=0.f;
  #pragma unroll
  for(int i=0;i<NC_;i++) S += rp[i*4+1]*__expf(rp[i*4]-M);
  float invS = 1.f/S;
  float LMIN=1e30f;
  #pragma unroll
  for(int i=0;i<NC_;i++) LMIN=fminf(LMIN, rp[i*4+2]);
  float amin = __expf(LMIN-M)*invS;
  float dinv = 1.f/(invS - amin + 1e-5f);
  const float* lp = lgt + (size_t)bk*N_ + chunk*CS_;
  {
    float p = __expf(lp[tid]-M)*invS;
    psp[tid]=p;
    out_attn[(size_t)bk*N_ + chunk*CS_ + tid] = (p - amin)*dinv;
  }
  __syncthreads();
  const float* Fb = featc + ((size_t)b*N_ + chunk*CS_)*16;
  float ac=0.f;
  for(int t=0;t<16;t++){
    int n = wid*64 + t*4 + sub;
    ac += psp[n]*Fb[(size_t)n*16 + c4];
  }
  ac+=__shfl_xor(ac,16,64); ac+=__shfl_xor(ac,32,64);
  if(lane<16) pcz[wid][lane]=ac;
  __syncthreads();
  if(tid<16){
    float s2 = pcz[0][tid]+pcz[1][tid]+pcz[2][tid]+pcz[3][tid];
    atomicAdd(&out_slot[bk*80+64+tid], s2);
  }
  if(chunk==0 && tid<64) out_slot[bk*80+tid]=sl1[bk*64+tid];
}

extern "C" void kernel_launch(void* const* d_in, const int* in_sizes, int n_in,
                              void* d_out, int out_size, void* d_ws, size_t ws_size,
                              hipStream_t stream){
  (void)in_sizes; (void)n_in; (void)out_size; (void)ws_size;
  const float* feat = (const float*)d_in[0];
  const float* featc= (const float*)d_in[1];
  const float* mask = (const float*)d_in[2];
  const float* noise= (const float*)d_in[3];
  const float* mu   = (const float*)d_in[4];
  const float* lsg  = (const float*)d_in[5];
  const float* wg   = (const float*)d_in[6];
  const float* bg   = (const float*)d_in[7];
  const float* wk   = (const float*)d_in[8];
  const float* wv   = (const float*)d_in[9];
  const float* lnkg = (const float*)d_in[10];
  const float* lnkb = (const float*)d_in[11];
  const float* wm   = (const float*)d_in[12];
  const float* bm   = (const float*)d_in[13];
  const float* lnqg = (const float*)d_in[14];
  const float* lnqb = (const float*)d_in[15];
  const float* wq   = (const float*)d_in[16];
  const float* wih  = (const float*)d_in[17];
  const float* whh  = (const float*)d_in[18];
  const float* bih  = (const float*)d_in[19];
  const float* bhh  = (const float*)d_in[20];
  const float* lnfg = (const float*)d_in[21];
  const float* lnfb = (const float*)d_in[22];
  const float* lncg = (const float*)d_in[23];
  const float* lncb = (const float*)d_in[24];
  const float* lnrg = (const float*)d_in[25];
  const float* lnrb = (const float*)d_in[26];
  const float* wres = (const float*)d_in[27];
  const float* bres = (const float*)d_in[28];

  float* out = (float*)d_out;
  float* out_slot = out;          // (B,K,80)
  float* out_fg   = out + 6400;   // (B,K,2)
  float* out_attn = out + 6560;   // (B,K,N)

  float* wsf     = (float*)d_ws;
  float* ws_fg   = wsf;                                // 16
  float* ws_bm2  = wsf + 16;                           // 64
  float* ws_fkb  = ws_bm2 + 64;                        // 64
  float* ws_fvb  = ws_fkb + 64;                        // 64
  float* ws_qb   = ws_fvb + 64;                        // 64
  float* ws_br2  = ws_qb + 64;                         // 64
  float* ws_wgx  = ws_br2 + 64;                        // 64
  float* ws_wgy  = ws_wgx + 64;                        // 64
  float* ws_gs   = ws_wgy + 64;                        // 16
  float* ws_wqpT = ws_gs + 16;                         // 4096
  float* ws_wrpT = ws_wqpT + 4096;                     // 4096
  float* ws_wvT  = ws_wrpT + 4096;                     // 4096
  float* ws_wmT  = ws_wvT + 4096;                      // 4096
  float* ws_gw   = ws_wmT + 4096;                      // 24576
  float* ws_fc   = ws_gw + 24576;                      // B*N*C
  float* ws_sl0  = ws_fc + (size_t)B_*N_*C_;           // 5120
  float* ws_sl1  = ws_sl0 + B_*K_*D_;                  // 5120
  float* ws_lgt  = ws_sl1 + B_*K_*D_;                  // B*K*N
  float* ws_red0 = ws_lgt + (size_t)B_*K_*N_;          // 80*NC*4
  float* ws_red1 = ws_red0 + B_*K_*NC_*4;              // 80*NC*4
  float* ws_prt0 = ws_red1 + B_*K_*NC_*4;              // 80*NC*64
  float* ws_prt1 = ws_prt0 + (size_t)B_*K_*NC_*64;     // 80*NC*64
  float* ws_psc0 = ws_prt1 + (size_t)B_*K_*NC_*64;     // 80*NC*4
  float* ws_psc1 = ws_psc0 + B_*K_*NC_*4;              // 80*NC*4
  float4* ws_kst = (float4*)(ws_psc1 + B_*K_*NC_*4);   // B*N float4
  float4* ws_vst = ws_kst + (size_t)B_*N_;             // B*N float4
  uint16_t* ws_A = (uint16_t*)(ws_vst + (size_t)B_*N_);// B*N*64 bf16

  k_pre<<<187,256,0,stream>>>(mask,noise,mu,lsg, wm,bm,lnkb, wk,wv,lnfb,
                              wq,lnqg,lnqb, wres,bres,lnrg,lnrb, wih,whh, wg,bg,
                              ws_fg,out_fg, ws_bm2,ws_fkb,ws_fvb,ws_qb,ws_br2,
                              ws_wgx,ws_wgy,ws_gs,
                              ws_wqpT,ws_wrpT,ws_wvT,ws_wmT, ws_gw, ws_sl0, out_slot);
  k_featln<<<(B_*N_)/64,256,0,stream>>>(feat,wk,wv,lnfg,ws_fkb,ws_fvb,
                                        ws_wgx,ws_wgy,bg,
                                        featc,lncg,lncb,
                                        ws_A,ws_kst,ws_vst,ws_fc);

  AttnP P;
  P.Aw=ws_A; P.kst=ws_kst; P.vst=ws_vst;
  P.gw=ws_gw; P.bih=bih; P.bhh=bhh;
  P.wrpT=ws_wrpT; P.br2=ws_br2; P.wqpT=ws_wqpT; P.qb=ws_qb;
  P.wm=wm; P.wk=wk; P.lnfg=lnfg; P.lnkg=lnkg;
  P.fkb=ws_fkb; P.bm2=ws_bm2; P.fvb=ws_fvb;
  P.wvT=ws_wvT; P.wmT=ws_wmT;
  P.wgx=ws_wgx; P.wgy=ws_wgy; P.bg=bg;
  P.gs=ws_gs; P.fg=ws_fg; P.lgt=ws_lgt;

  dim3 agrid(NC_,B_);
  // it0: q from sl0; out -> red0/prt0/psc0
  k_attn<false,false><<<agrid,256,0,stream>>>(P, ws_sl0, ws_sl0,
      ws_prt1, ws_psc1, ws_red1, ws_red0, ws_prt0, ws_psc0);
  // it1: GRU(sl0)->sl1; in 0, out 1
  k_attn<true,false><<<agrid,256,0,stream>>>(P, ws_sl0, ws_sl1,
      ws_prt0, ws_psc0, ws_red0, ws_red1, ws_prt1, ws_psc1);
  // it2: GRU(sl1)->sl0; in 1, out 0
  k_attn<true,false><<<agrid,256,0,stream>>>(P, ws_sl1, ws_sl0,
      ws_prt1, ws_psc1, ws_red1, ws_red0, ws_prt0, ws_psc0);
  // it3 (final): GRU(sl0)->sl1; in 0, out red1
  k_attn<true,true><<<agrid,256,0,stream>>>(P, ws_sl0, ws_sl1,
      ws_prt0, ws_psc0, ws_red0, ws_red1, ws_prt1, ws_psc1);
  k_fin<<<dim3(NC_,B_*K_),256,0,stream>>>(ws_lgt,ws_red1,ws_fc,ws_sl1,out_slot,out_attn);
}

// Round 14
// 222.502 us; speedup vs baseline: 1.1471x; 1.1471x over previous
//
#include <hip/hip_runtime.h>
#include <stdint.h>

#define B_ 16
#define H_ 64
#define W_ 64
#define D_ 64
#define C_ 16
#define K_ 5
#define N_ 4096
#define NC_ 32         // attention n-chunks
#define CS_ 128        // chunk size = N_/NC_
#define EPS 1e-5f

typedef __attribute__((ext_vector_type(8))) short bf16x8;
typedef __attribute__((ext_vector_type(4))) float f32x4;

__device__ __forceinline__ float wsum64(float v){
  #pragma unroll
  for(int o=1;o<64;o<<=1) v += __shfl_xor(v,o,64);
  return v;
}
__device__ __forceinline__ float wmax64(float v){
  #pragma unroll
  for(int o=1;o<64;o<<=1) v = fmaxf(v, __shfl_xor(v,o,64));
  return v;
}
__device__ __forceinline__ float wmin64(float v){
  #pragma unroll
  for(int o=1;o<64;o<<=1) v = fminf(v, __shfl_xor(v,o,64));
  return v;
}
__device__ __forceinline__ uint16_t f2bf(float f){
  uint32_t u = __float_as_uint(f);
  u += 0x7fffu + ((u>>16)&1u);
  return (uint16_t)(u>>16);
}

// k_pre: fgpos (0-4) + folded biases (5) + fvb/wgx/wgy/gscal/out_slot-zero (6)
// + wqpT/wrpT/wvT/wmT (7-70) + gw (71-166) + slot init (167-186)
__global__ __launch_bounds__(256) void k_pre(
    const float* __restrict__ mask, const float* __restrict__ noise,
    const float* __restrict__ mu, const float* __restrict__ lsg,
    const float* __restrict__ wm, const float* __restrict__ bm, const float* __restrict__ lnkb,
    const float* __restrict__ wk, const float* __restrict__ wv, const float* __restrict__ lnfb,
    const float* __restrict__ wq, const float* __restrict__ lnqg, const float* __restrict__ lnqb,
    const float* __restrict__ wres, const float* __restrict__ bres,
    const float* __restrict__ lnrg, const float* __restrict__ lnrb,
    const float* __restrict__ wih, const float* __restrict__ whh,
    const float* __restrict__ wg, const float* __restrict__ bg,
    float* __restrict__ ws_fg, float* __restrict__ out_fg,
    float* __restrict__ bm2, float* __restrict__ fkb, float* __restrict__ fvb,
    float* __restrict__ qb, float* __restrict__ br2,
    float* __restrict__ wgx, float* __restrict__ wgy, float* __restrict__ gscal,
    float* __restrict__ wqpT, float* __restrict__ wrpT,
    float* __restrict__ wvT, float* __restrict__ wmT,
    float* __restrict__ gw, float* __restrict__ slot, float* __restrict__ out_slot){
  int bid=blockIdx.x, tid=threadIdx.x;
  if(bid<5){
    int k=bid;
    float sm=0.f, sx=0.f, sy=0.f;
    for(int p=tid; p<H_*W_; p+=256){
      int i=p>>6, j=p&63;
      float m = mask[k*H_*W_ + p];
      float x = -1.f + (2.f/63.f)*j;
      float y = -1.f + (2.f/63.f)*i;
      sm+=m; sx+=m*x; sy+=m*y;
    }
    __shared__ float r0[4], r1[4], r2[4];
    int wid=tid>>6, lane=tid&63;
    sm=wsum64(sm); sx=wsum64(sx); sy=wsum64(sy);
    if(lane==0){ r0[wid]=sm; r1[wid]=sx; r2[wid]=sy; }
    __syncthreads();
    if(tid==0){
      float tm=r0[0]+r0[1]+r0[2]+r0[3];
      float tx=r1[0]+r1[1]+r1[2]+r1[3];
      float ty=r2[0]+r2[1]+r2[2]+r2[3];
      float px = tx/(tm+1e-5f), py = ty/(tm+1e-5f);
      ws_fg[k*2+0]=px; ws_fg[k*2+1]=py;
      for(int b=0;b<B_;b++){ out_fg[(b*K_+k)*2+0]=px; out_fg[(b*K_+k)*2+1]=py; }
    }
  } else if(bid==5){
    int sel=tid>>6, o=tid&63; float s=0.f;
    if(sel==0){ s=bm[o]; for(int d=0;d<64;d++) s+=lnkb[d]*wm[o*64+d]; bm2[o]=s; }
    else if(sel==1){ for(int d=0;d<64;d++) s+=lnqb[d]*wq[o*64+d]; qb[o]=0.125f*s; }
    else if(sel==2){ for(int d=0;d<64;d++) s+=lnrb[d]*wres[o*64+d]; br2[o]=s+bres[o]; }
    else { for(int d=0;d<64;d++) s+=lnfb[d]*wk[o*64+d]; fkb[o]=s; }
  } else if(bid==6){
    int wv4=tid>>6, l=tid&63;
    if(wv4==0){ float s=0.f; for(int d=0;d<64;d++) s+=lnfb[d]*wv[l*64+d]; fvb[l]=s; }
    else if(wv4==1){
      float4 w4 = *(const float4*)(wg + l*4);
      wgx[l]=w4.x-w4.z; wgy[l]=w4.y-w4.w;
    } else if(wv4==2){
      float4 w4 = *(const float4*)(wg + l*4);
      float wx=w4.x-w4.z, wy=w4.y-w4.w, bl=bg[l];
      float t;
      t=wsum64(wx);    if(l==0) gscal[0]=t*(1.f/64.f);
      t=wsum64(wy);    if(l==0) gscal[1]=t*(1.f/64.f);
      t=wsum64(bl);    if(l==0) gscal[2]=t*(1.f/64.f);
      t=wsum64(wx*wx); if(l==0) gscal[3]=t*(1.f/64.f);
      t=wsum64(wy*wy); if(l==0) gscal[4]=t*(1.f/64.f);
      t=wsum64(wx*wy); if(l==0) gscal[5]=t*(2.f/64.f);
      t=wsum64(wx*bl); if(l==0) gscal[6]=t*(2.f/64.f);
      t=wsum64(wy*bl); if(l==0) gscal[7]=t*(2.f/64.f);
      t=wsum64(bl*bl); if(l==0) gscal[8]=t*(1.f/64.f);
    } else {
      for(int j=l;j<B_*K_*16;j+=64){ int bk2=j>>4, cc2=j&15; out_slot[bk2*80+64+cc2]=0.f; }
    }
  } else if(bid<71){
    int i=(bid-7)*256+tid;           // < 16384
    int a=i>>12, r=i&4095, d=r>>6, o=r&63;
    if(a==0)      wqpT[r]=0.125f*lnqg[d]*wq[o*64+d];
    else if(a==1) wrpT[r]=lnrg[d]*wres[o*64+d];
    else if(a==2) wvT[r]=wv[o*64+d];
    else          wmT[r]=wm[o*64+d];
  } else if(bid<167){
    int i=(bid-71)*256+tid;          // < 24576
    int g6=i>>12, r=i&4095, d=r>>6, o=r&63;
    float v = (g6<3)? wih[(g6*64+o)*64+d] : whh[((g6-3)*64+o)*64+d];
    gw[g6*4096 + d*64 + o] = v;
  } else {
    int i=(bid-167)*256+tid;
    if(i<B_*K_*D_){ int d=i&63; slot[i]=mu[d]+expf(lsg[d])*noise[i]; }
  }
}

// feat LN -> A (bf16); transient MFMA fk/fv rows -> per-row stat float4s; color LN.
__global__ __launch_bounds__(256) void k_featln(const float* __restrict__ feat,
    const float* __restrict__ wk, const float* __restrict__ wv, const float* __restrict__ gf,
    const float* __restrict__ fkb, const float* __restrict__ fvb,
    const float* __restrict__ wgx, const float* __restrict__ wgy, const float* __restrict__ bg,
    const float* __restrict__ fc, const float* __restrict__ gc, const float* __restrict__ bc,
    uint16_t* __restrict__ Aout, float4* __restrict__ kstat, float4* __restrict__ vstat,
    float* __restrict__ fcn){
  int tid=threadIdx.x, wid=tid>>6, lane=tid&63;
  int q=lane>>4, c=lane&15;
  size_t row = (size_t)blockIdx.x*64 + wid*16 + c;
  const float* xp = feat + row*64;
  float x[16];
  *(float4*)&x[0]  = *(const float4*)(xp + q*8);
  *(float4*)&x[4]  = *(const float4*)(xp + q*8 + 4);
  *(float4*)&x[8]  = *(const float4*)(xp + 32 + q*8);
  *(float4*)&x[12] = *(const float4*)(xp + 36 + q*8);
  float s=0.f;
  #pragma unroll
  for(int i=0;i<16;i++) s+=x[i];
  s += __shfl_xor(s,16,64); s += __shfl_xor(s,32,64);
  float mean = s*(1.f/64.f);
  float v=0.f;
  #pragma unroll
  for(int i=0;i<16;i++){ float d=x[i]-mean; v+=d*d; }
  v += __shfl_xor(v,16,64); v += __shfl_xor(v,32,64);
  float rs = rsqrtf(v*(1.f/64.f)+EPS);
  float gl[16];
  *(float4*)&gl[0]  = *(const float4*)(gf + q*8);
  *(float4*)&gl[4]  = *(const float4*)(gf + q*8 + 4);
  *(float4*)&gl[8]  = *(const float4*)(gf + 32 + q*8);
  *(float4*)&gl[12] = *(const float4*)(gf + 36 + q*8);
  bf16x8 A0, A1;
  #pragma unroll
  for(int j=0;j<8;j++){
    A0[j] = (short)f2bf((x[j]  -mean)*rs);
    A1[j] = (short)f2bf((x[8+j]-mean)*rs);
  }
  *(bf16x8*)(Aout + row*64 + q*8) = A0;
  *(bf16x8*)(Aout + row*64 + 32 + q*8) = A1;
  float wgxl[4][4], wgyl[4][4], bgl[4][4];
  #pragma unroll
  for(int ot=0;ot<4;ot++){
    *(float4*)&wgxl[ot][0] = *(const float4*)(wgx + ot*16 + q*4);
    *(float4*)&wgyl[ot][0] = *(const float4*)(wgy + ot*16 + q*4);
    *(float4*)&bgl[ot][0]  = *(const float4*)(bg + ot*16 + q*4);
  }
  #pragma unroll
  for(int mat=0;mat<2;mat++){
    const float* w = mat? wv : wk;
    const float* fb = mat? fvb : fkb;
    float ss=0.f, s2=0.f, dx=0.f, dy=0.f, db=0.f;
    #pragma unroll
    for(int ot=0; ot<4; ot++){
      const float* wp = w + (size_t)(ot*16+c)*64 + q*8;
      bf16x8 W0, W1;
      #pragma unroll
      for(int j=0;j<8;j++){ W0[j]=(short)f2bf(wp[j]*gl[j]); W1[j]=(short)f2bf(wp[32+j]*gl[8+j]); }
      float4 bq = *(const float4*)(fb + ot*16 + q*4);
      f32x4 acc = {bq.x,bq.y,bq.z,bq.w};
      acc = __builtin_amdgcn_mfma_f32_16x16x32_bf16(W0, A0, acc, 0,0,0);
      acc = __builtin_amdgcn_mfma_f32_16x16x32_bf16(W1, A1, acc, 0,0,0);
      #pragma unroll
      for(int r=0;r<4;r++){
        float a=acc[r];
        ss+=a; s2+=a*a;
        dx = fmaf(a, wgxl[ot][r], dx);
        dy = fmaf(a, wgyl[ot][r], dy);
        db = fmaf(a, bgl[ot][r], db);
      }
    }
    ss += __shfl_xor(ss,16,64); ss += __shfl_xor(ss,32,64);
    s2 += __shfl_xor(s2,16,64); s2 += __shfl_xor(s2,32,64);
    dx += __shfl_xor(dx,16,64); dx += __shfl_xor(dx,32,64);
    dy += __shfl_xor(dy,16,64); dy += __shfl_xor(dy,32,64);
    db += __shfl_xor(db,16,64); db += __shfl_xor(db,32,64);
    if(lane<16){
      size_t row2 = (size_t)blockIdx.x*64 + wid*16 + lane;
      float4 st = { ss*(1.f/64.f), s2*(1.f/64.f)+db*(1.f/32.f), dx*(1.f/32.f), dy*(1.f/32.f) };
      (mat? vstat : kstat)[row2] = st;
    }
  }
  int r16=tid>>4, cc=tid&15;
  #pragma unroll
  for(int i=0;i<4;i++){
    size_t row2 = (size_t)blockIdx.x*64 + i*16 + r16;
    float xv = fc[row2*16+cc];
    float sc=xv;
    #pragma unroll
    for(int o=1;o<16;o<<=1) sc += __shfl_xor(sc,o,16);
    float m2 = sc*(1.f/16.f);
    float df = xv-m2;
    float v2 = df*df;
    #pragma unroll
    for(int o=1;o<16;o<<=1) v2 += __shfl_xor(v2,o,16);
    fcn[row2*16+cc] = df*rsqrtf(v2*(1.f/16.f)+EPS)*gc[cc] + bc[cc];
  }
}

// Block-parallel per-bk preamble: GRU merge + q chain. 80 blocks x 256 threads.
// NC_=32 merge is lane-parallel (lane per chunk) + 4-wave partials for sA.
template<bool GRU>
__global__ __launch_bounds__(256) void k_slotq(
    const float* __restrict__ slot_prev, float* __restrict__ slot_cur,
    const float* __restrict__ part, const float* __restrict__ pscal,
    const float* __restrict__ red_in,
    const float* __restrict__ gw,
    const float* __restrict__ bih, const float* __restrict__ bhh,
    const float* __restrict__ wrpT, const float* __restrict__ br2,
    const float* __restrict__ wqpT, const float* __restrict__ qb,
    const float* __restrict__ wm, const float* __restrict__ wk,
    const float* __restrict__ lnfg, const float* __restrict__ lnkg,
    const float* __restrict__ fkb, const float* __restrict__ bm2, const float* __restrict__ fvb,
    const float* __restrict__ wvT, const float* __restrict__ wmT,
    const float* __restrict__ wgx, const float* __restrict__ wgy, const float* __restrict__ bg,
    const float* __restrict__ gscal,
    float* __restrict__ qs_out, float* __restrict__ cst_out){
  __shared__ float vv[64], vh[64];
  __shared__ float red6[4][64][6];
  __shared__ float lamb[NC_];
  int bk=blockIdx.x;
  int tid=threadIdx.x, wid=tid>>6, lane=tid&63;
  int o=lane, qq=wid;
  float mwgx=gscal[0], mwgy=gscal[1], mbg=gscal[2];

  #define MV(Wptr) { float p_=0.f; \
      _Pragma("unroll") \
      for(int dd=0;dd<16;dd++) p_ = fmaf(vv[qq*16+dd], (Wptr)[(qq*16+dd)*64+o], p_); \
      red6[qq][o][0]=p_; } __syncthreads();
  #define SUM0 (red6[0][lane][0]+red6[1][lane][0]+red6[2][lane][0]+red6[3][lane][0])

  float cur=0.f, qv=0.f, qp=0.f, hp=0.f;
  if(GRU){
    float As=0.f, Ax=0.f, Ay=0.f, Am=0.f;
    if(wid==0){
      // lane-parallel chunk merge (lane<NC_)
      float m_l = (lane<NC_)? red_in[((size_t)bk*NC_+lane)*4]   : -1e30f;
      float s_l = (lane<NC_)? red_in[((size_t)bk*NC_+lane)*4+1] : 0.f;
      float M = wmax64(m_l);
      float eu = (lane<NC_)? __expf(m_l-M) : 0.f;
      float S = wsum64(s_l*eu);
      float lam = eu/S;
      if(lane<NC_) lamb[lane]=lam;
      float p0 = (lane<NC_)? pscal[((size_t)bk*NC_+lane)*4+0] : 0.f;
      float p1 = (lane<NC_)? pscal[((size_t)bk*NC_+lane)*4+1] : 0.f;
      float p2 = (lane<NC_)? pscal[((size_t)bk*NC_+lane)*4+2] : 0.f;
      float p3 = (lane<NC_)? pscal[((size_t)bk*NC_+lane)*4+3] : 0.f;
      As = wsum64(lam*p0); Ax = wsum64(lam*p1);
      Ay = wsum64(lam*p2); Am = wsum64(lam*p3);
    }
    __syncthreads();
    { // sA partials: wave qq handles chunks qq*8..qq*8+7
      float p_=0.f;
      #pragma unroll
      for(int j=0;j<8;j++){
        int cc = qq*8+j;
        p_ = fmaf(lamb[cc], part[((size_t)bk*NC_+cc)*64+o], p_);
      }
      red6[qq][o][0]=p_;
    }
    __syncthreads();
    if(wid==0){
      float sA = SUM0;
      vv[lane] = lnfg[lane]*sA;
    }
    __syncthreads();
    MV(wvT);
    if(wid==0){
      float fvs = SUM0 + fvb[lane]*As;
      float zs = fvs + Ax*wgx[lane] + Ay*wgy[lane] + As*bg[lane] - Am;
      vv[lane] = lnkg[lane]*zs;
    }
    __syncthreads();
    MV(wmT);
    if(wid==0){
      float x_ = SUM0 + bm2[lane];
      hp = slot_prev[bk*64+lane];
      vv[lane]=x_; vh[lane]=hp;
    }
    __syncthreads();
    {
      float p0=0.f,p1=0.f,p2=0.f,p3=0.f,p4=0.f,p5=0.f;
      #pragma unroll
      for(int dd=0;dd<16;dd++){
        int d = qq*16+dd;
        float xd=vv[d], hd=vh[d];
        p0 = fmaf(xd, gw[d*64+o], p0);
        p1 = fmaf(xd, gw[4096+d*64+o], p1);
        p2 = fmaf(xd, gw[8192+d*64+o], p2);
        p3 = fmaf(hd, gw[12288+d*64+o], p3);
        p4 = fmaf(hd, gw[16384+d*64+o], p4);
        p5 = fmaf(hd, gw[20480+d*64+o], p5);
      }
      red6[qq][o][0]=p0; red6[qq][o][1]=p1; red6[qq][o][2]=p2;
      red6[qq][o][3]=p3; red6[qq][o][4]=p4; red6[qq][o][5]=p5;
    }
    __syncthreads();
    if(wid==0){
      float gir=bih[lane], giz=bih[64+lane], gin=bih[128+lane];
      float ghr=bhh[lane], ghz=bhh[64+lane], ghn=bhh[128+lane];
      #pragma unroll
      for(int w=0;w<4;w++){
        gir+=red6[w][lane][0]; giz+=red6[w][lane][1]; gin+=red6[w][lane][2];
        ghr+=red6[w][lane][3]; ghz+=red6[w][lane][4]; ghn+=red6[w][lane][5];
      }
      float r=1.f/(1.f+__expf(-(gir+ghr)));
      float z=1.f/(1.f+__expf(-(giz+ghz)));
      float nn=tanhf(gin+r*ghn);
      float sp=(1.f-z)*nn+z*hp;
      float m=wsum64(sp)*(1.f/64.f); float df=sp-m;
      float var=wsum64(df*df)*(1.f/64.f);
      vv[lane]=df*rsqrtf(var+EPS);
    }
    __syncthreads();
    MV(wrpT);
    if(wid==0){
      cur = SUM0 + br2[lane] + hp;
      slot_cur[bk*64+lane]=cur;
    }
  } else {
    if(wid==0) cur = slot_prev[bk*64+lane];
  }
  __syncthreads();
  if(wid==0){
    float m=wsum64(cur)*(1.f/64.f); float df=cur-m;
    float var=wsum64(df*df)*(1.f/64.f);
    vv[lane]=df*rsqrtf(var+EPS);
  }
  __syncthreads();
  MV(wqpT);
  if(wid==0){ qv = SUM0 + qb[lane]; vv[lane]=qv; }
  __syncthreads();
  MV(wm);
  if(wid==0){ qp = SUM0*lnkg[lane]; vv[lane]=qp; }
  __syncthreads();
  MV(wk);
  if(wid==0){
    qs_out[bk*64+lane] = SUM0*lnfg[lane];
    float s1 = wsum64(qp);
    float c1 = wsum64(qp*wgx[lane]);
    float c2 = wsum64(qp*wgy[lane]);
    float c3 = wsum64(qp*(bg[lane]+fkb[lane]));
    float c4c = wsum64(qv*bm2[lane]);
    if(lane==0){
      float* cp = cst_out + bk*8;
      cp[0]=c1-s1*mwgx; cp[1]=c2-s1*mwgy; cp[2]=c3-s1*mbg; cp[3]=s1; cp[4]=c4c;
    }
  }
  #undef MV
  #undef SUM0
}

// Slot-amortized attention: block = (chunk CS_=128, b), all K=5 slots.
// Batched phase-2 (2 barriers). Grid (NC_=32, B_) = 512 blocks.
template<bool FINAL>
__global__ __launch_bounds__(256) void k_attn(const uint16_t* __restrict__ Aw,
    const float4* __restrict__ kstat, const float4* __restrict__ vstat,
    const float* __restrict__ qsg, const float* __restrict__ cstg,
    const float* __restrict__ gscal, const float* __restrict__ ws_fg,
    float* __restrict__ lgt, float* __restrict__ red_out,
    float* __restrict__ part_o, float* __restrict__ pscal_o){
  __shared__ uint32_t As_[CS_*32];      // 16KB: 128 rows x 64 bf16
  __shared__ float dps[5][CS_+4];       // dots -> weights
  __shared__ float pw[4][5][64];
  __shared__ float rm[2][5], rn[2][5];
  __shared__ float rsc[2][5][5];
  __shared__ float cstl[5][5];
  __shared__ float fgl[5][2];
  int chunk=blockIdx.x, b=blockIdx.y;
  int tid=threadIdx.x, wid=tid>>6, lane=tid&63;
  int c=lane&15, q=lane>>4;
  float mwgx=gscal[0], mwgy=gscal[1], mbg=gscal[2];
  float g1=gscal[3], g2=gscal[4], g3=gscal[5], g4=gscal[6], g5=gscal[7], g6=gscal[8];

  // stage A chunk -> LDS
  const uint4* Ag = (const uint4*)(Aw + ((size_t)b*N_ + chunk*CS_)*64);
  #pragma unroll
  for(int jj=0;jj<4;jj++){
    int f = jj*256 + tid;
    *(uint4*)(As_ + f*4) = Ag[f];
  }
  if(tid<25) cstl[tid/5][tid%5] = cstg[(b*K_ + tid/5)*8 + (tid%5)];
  if(tid>=32 && tid<42){ int i2=tid-32; fgl[i2>>1][i2&1] = ws_fg[i2]; }
  // per-thread row stats (rows 0..127 -> threads 0..127)
  bool act = tid < CS_;
  int nrow = chunk*CS_ + (tid & (CS_-1));
  float4 st, sv;
  float gx=0.f, gy=0.f;
  if(act){
    st = kstat[(size_t)b*N_ + nrow];
    if(!FINAL) sv = vstat[(size_t)b*N_ + nrow];
    gx = -1.f + (2.f/63.f)*(nrow&63);
    gy = -1.f + (2.f/63.f)*(nrow>>6);
  }
  __syncthreads();

  // phase 1: MFMA dots; B-frags from GLOBAL (aligned); 2 tiles per wave
  {
    bf16x8 QF0={0,0,0,0,0,0,0,0}, QF1={0,0,0,0,0,0,0,0};
    if(c<5){
      const float* qpp = qsg + (b*K_+c)*64;
      #pragma unroll
      for(int j=0;j<8;j++){
        QF0[j] = (short)f2bf(qpp[q*8+j]);
        QF1[j] = (short)f2bf(qpp[32+q*8+j]);
      }
    }
    const uint16_t* Abase = Aw + ((size_t)b*N_ + chunk*CS_)*64;
    #pragma unroll
    for(int it=0;it<2;it++){
      int tile = wid*32 + it*16;
      const uint16_t* rp = Abase + (size_t)(tile+c)*64;
      bf16x8 BF0 = *(const bf16x8*)(rp + q*8);
      bf16x8 BF1 = *(const bf16x8*)(rp + 32 + q*8);
      f32x4 acc = {0.f,0.f,0.f,0.f};
      acc = __builtin_amdgcn_mfma_f32_16x16x32_bf16(QF0, BF0, acc, 0,0,0);
      acc = __builtin_amdgcn_mfma_f32_16x16x32_bf16(QF1, BF1, acc, 0,0,0);
      #pragma unroll
      for(int r=0;r<4;r++){
        int s = q*4+r;
        if(s<5) dps[s][tile+c]=acc[r];
      }
    }
  }
  __syncthreads();

  // phase 2 (batched over slots; 2 barriers)
  float l5[5], w5[5];
  if(act){
    #pragma unroll
    for(int k=0;k<5;k++){
      float rx = gx - fgl[k][0], ry = gy - fgl[k][1];
      float CX=cstl[k][0], CY=cstl[k][1], C0=cstl[k][2], S1=cstl[k][3], C4=cstl[k][4];
      float quad = g1*rx*rx + g2*ry*ry + g3*rx*ry + g4*rx + g5*ry + g6;
      float mu = st.x + rx*mwgx + ry*mwgy + mbg;
      float var = st.y + rx*st.z + ry*st.w + quad - mu*mu;
      float rsn = rsqrtf(var+EPS);
      float l = rsn*(dps[k][tid] + rx*CX + ry*CY + C0 - S1*st.x) + C4;
      l5[k]=l;
      float wmx = wmax64(l);
      if(lane==0) rm[wid][k]=wmx;
      if(FINAL){ float mn=wmin64(l); if(lane==0) rn[wid][k]=mn; }
    }
  }
  __syncthreads();
  if(act){
    #pragma unroll
    for(int k=0;k<5;k++){
      float m_c = fmaxf(rm[0][k], rm[1][k]);
      float e = __expf(l5[k]-m_c);
      float scq = wsum64(e);
      if(!FINAL){
        float rx = gx - fgl[k][0], ry = gy - fgl[k][1];
        float quad = g1*rx*rx + g2*ry*ry + g3*rx*ry + g4*rx + g5*ry + g6;
        float muV = sv.x + rx*mwgx + ry*mwgy + mbg;
        float varV = sv.y + rx*sv.z + ry*sv.w + quad - muV*muV;
        float rsv_ = rsqrtf(varV+EPS);
        float w_ = e*rsv_;
        w5[k]=w_;
        float As2=wsum64(w_), Ax2=wsum64(w_*rx), Ay2=wsum64(w_*ry), Am2=wsum64(w_*muV);
        if(lane==0){ rsc[wid][k][0]=scq; rsc[wid][k][1]=As2; rsc[wid][k][2]=Ax2;
                     rsc[wid][k][3]=Ay2; rsc[wid][k][4]=Am2; }
      } else {
        lgt[(size_t)(b*K_+k)*N_ + nrow] = l5[k];
        if(lane==0) rsc[wid][k][0]=scq;
      }
    }
  }
  __syncthreads();
  if(tid<5){
    int k=tid;
    size_t idx = ((size_t)(b*K_+k)*NC_+chunk)*4;
    red_out[idx+0]=fmaxf(rm[0][k],rm[1][k]);
    red_out[idx+1]=rsc[0][k][0]+rsc[1][k][0];
    if(FINAL) red_out[idx+2]=fminf(rn[0][k],rn[1][k]);
    if(!FINAL){
      pscal_o[idx+0]=rsc[0][k][1]+rsc[1][k][1];
      pscal_o[idx+1]=rsc[0][k][2]+rsc[1][k][2];
      pscal_o[idx+2]=rsc[0][k][3]+rsc[1][k][3];
      pscal_o[idx+3]=rsc[0][k][4]+rsc[1][k][4];
    }
  }
  if(act && !FINAL){
    #pragma unroll
    for(int k=0;k<5;k++) dps[k][tid]=w5[k];
  }

  // accumulation: part[k][ch] = sum_row w_k[row]*A[row][ch]
  if(!FINAL){
    __syncthreads();
    const uint16_t* Au = (const uint16_t*)As_;
    float a[5]={0.f,0.f,0.f,0.f,0.f};
    for(int r32=0;r32<32;r32++){
      int row = wid*32 + r32;
      float av = __uint_as_float(((uint32_t)Au[row*64+lane])<<16);
      #pragma unroll
      for(int k=0;k<5;k++) a[k]=fmaf(dps[k][row], av, a[k]);
    }
    #pragma unroll
    for(int k=0;k<5;k++) pw[wid][k][lane]=a[k];
    __syncthreads();
    if(tid<64){
      #pragma unroll
      for(int k=0;k<5;k++){
        float s2 = pw[0][k][tid]+pw[1][k][tid]+pw[2][k][tid]+pw[3][k][tid];
        part_o[((size_t)(b*K_+k)*NC_+chunk)*64 + tid] = s2;
      }
    }
  }
}

// fin: p from global stats; out_attn; color partial atomicAdd; slot write (chunk 0)
__global__ __launch_bounds__(256) void k_fin(const float* __restrict__ lgt,
    const float* __restrict__ red, const float* __restrict__ featc,
    const float* __restrict__ sl1, float* __restrict__ out_slot,
    float* __restrict__ out_attn){
  __shared__ float psp[CS_];
  __shared__ float pcz[4][16];
  int chunk=blockIdx.x, bk=blockIdx.y, b=bk/K_;
  int tid=threadIdx.x, wid=tid>>6, lane=tid&63, sub=lane>>4, c4=lane&15;
  const float* rp = red + (size_t)bk*NC_*4;
  float M=-1e30f;
  #pragma unroll
  for(int i=0;i<NC_;i++) M = fmaxf(M, rp[i*4]);
  float S=0.f;
  #pragma unroll
  for(int i=0;i<NC_;i++) S += rp[i*4+1]*__expf(rp[i*4]-M);
  float invS = 1.f/S;
  float LMIN=1e30f;
  #pragma unroll
  for(int i=0;i<NC_;i++) LMIN=fminf(LMIN, rp[i*4+2]);
  float amin = __expf(LMIN-M)*invS;
  float dinv = 1.f/(invS - amin + 1e-5f);
  const float* lp = lgt + (size_t)bk*N_ + chunk*CS_;
  if(tid<CS_){
    float p = __expf(lp[tid]-M)*invS;
    psp[tid]=p;
    out_attn[(size_t)bk*N_ + chunk*CS_ + tid] = (p - amin)*dinv;
  }
  __syncthreads();
  const float* Fb = featc + ((size_t)b*N_ + chunk*CS_)*16;
  float ac=0.f;
  for(int t=0;t<8;t++){
    int n = wid*32 + t*4 + sub;
    ac += psp[n]*Fb[(size_t)n*16 + c4];
  }
  ac+=__shfl_xor(ac,16,64); ac+=__shfl_xor(ac,32,64);
  if(lane<16) pcz[wid][lane]=ac;
  __syncthreads();
  if(tid<16){
    float s2 = pcz[0][tid]+pcz[1][tid]+pcz[2][tid]+pcz[3][tid];
    atomicAdd(&out_slot[bk*80+64+tid], s2);
  }
  if(chunk==0 && tid<64) out_slot[bk*80+tid]=sl1[bk*64+tid];
}

extern "C" void kernel_launch(void* const* d_in, const int* in_sizes, int n_in,
                              void* d_out, int out_size, void* d_ws, size_t ws_size,
                              hipStream_t stream){
  (void)in_sizes; (void)n_in; (void)out_size; (void)ws_size;
  const float* feat = (const float*)d_in[0];
  const float* featc= (const float*)d_in[1];
  const float* mask = (const float*)d_in[2];
  const float* noise= (const float*)d_in[3];
  const float* mu   = (const float*)d_in[4];
  const float* lsg  = (const float*)d_in[5];
  const float* wg   = (const float*)d_in[6];
  const float* bg   = (const float*)d_in[7];
  const float* wk   = (const float*)d_in[8];
  const float* wv   = (const float*)d_in[9];
  const float* lnkg = (const float*)d_in[10];
  const float* lnkb = (const float*)d_in[11];
  const float* wm   = (const float*)d_in[12];
  const float* bm   = (const float*)d_in[13];
  const float* lnqg = (const float*)d_in[14];
  const float* lnqb = (const float*)d_in[15];
  const float* wq   = (const float*)d_in[16];
  const float* wih  = (const float*)d_in[17];
  const float* whh  = (const float*)d_in[18];
  const float* bih  = (const float*)d_in[19];
  const float* bhh  = (const float*)d_in[20];
  const float* lnfg = (const float*)d_in[21];
  const float* lnfb = (const float*)d_in[22];
  const float* lncg = (const float*)d_in[23];
  const float* lncb = (const float*)d_in[24];
  const float* lnrg = (const float*)d_in[25];
  const float* lnrb = (const float*)d_in[26];
  const float* wres = (const float*)d_in[27];
  const float* bres = (const float*)d_in[28];

  float* out = (float*)d_out;
  float* out_slot = out;          // (B,K,80)
  float* out_fg   = out + 6400;   // (B,K,2)
  float* out_attn = out + 6560;   // (B,K,N)

  float* wsf     = (float*)d_ws;
  float* ws_fg   = wsf;                                // 16
  float* ws_bm2  = wsf + 16;                           // 64
  float* ws_fkb  = ws_bm2 + 64;                        // 64
  float* ws_fvb  = ws_fkb + 64;                        // 64
  float* ws_qb   = ws_fvb + 64;                        // 64
  float* ws_br2  = ws_qb + 64;                         // 64
  float* ws_wgx  = ws_br2 + 64;                        // 64
  float* ws_wgy  = ws_wgx + 64;                        // 64
  float* ws_gs   = ws_wgy + 64;                        // 16
  float* ws_wqpT = ws_gs + 16;                         // 4096
  float* ws_wrpT = ws_wqpT + 4096;                     // 4096
  float* ws_wvT  = ws_wrpT + 4096;                     // 4096
  float* ws_wmT  = ws_wvT + 4096;                      // 4096
  float* ws_gw   = ws_wmT + 4096;                      // 24576
  float* ws_fc   = ws_gw + 24576;                      // B*N*C
  float* ws_sl0  = ws_fc + (size_t)B_*N_*C_;           // 5120
  float* ws_sl1  = ws_sl0 + B_*K_*D_;                  // 5120
  float* ws_qs   = ws_sl1 + B_*K_*D_;                  // 5120
  float* ws_cst  = ws_qs + B_*K_*D_;                   // 640
  float* ws_lgt  = ws_cst + 640;                       // B*K*N
  float* ws_red0 = ws_lgt + (size_t)B_*K_*N_;          // 80*NC*4
  float* ws_red1 = ws_red0 + B_*K_*NC_*4;              // 80*NC*4
  float* ws_prt0 = ws_red1 + B_*K_*NC_*4;              // 80*NC*64
  float* ws_prt1 = ws_prt0 + (size_t)B_*K_*NC_*64;     // 80*NC*64
  float* ws_psc0 = ws_prt1 + (size_t)B_*K_*NC_*64;     // 80*NC*4
  float* ws_psc1 = ws_psc0 + B_*K_*NC_*4;              // 80*NC*4
  float4* ws_kst = (float4*)(ws_psc1 + B_*K_*NC_*4);   // B*N float4
  float4* ws_vst = ws_kst + (size_t)B_*N_;             // B*N float4
  uint16_t* ws_A = (uint16_t*)(ws_vst + (size_t)B_*N_);// B*N*64 bf16

  k_pre<<<187,256,0,stream>>>(mask,noise,mu,lsg, wm,bm,lnkb, wk,wv,lnfb,
                              wq,lnqg,lnqb, wres,bres,lnrg,lnrb, wih,whh, wg,bg,
                              ws_fg,out_fg, ws_bm2,ws_fkb,ws_fvb,ws_qb,ws_br2,
                              ws_wgx,ws_wgy,ws_gs,
                              ws_wqpT,ws_wrpT,ws_wvT,ws_wmT, ws_gw, ws_sl0, out_slot);
  k_featln<<<(B_*N_)/64,256,0,stream>>>(feat,wk,wv,lnfg,ws_fkb,ws_fvb,
                                        ws_wgx,ws_wgy,bg,
                                        featc,lncg,lncb,
                                        ws_A,ws_kst,ws_vst,ws_fc);

  dim3 agrid(NC_,B_);
  #define SQ_ARGS(SPREV,SCUR,PIN,SCIN,RIN) SPREV,SCUR,PIN,SCIN,RIN,ws_gw, \
      bih,bhh,ws_wrpT,ws_br2,ws_wqpT,ws_qb, wm,wk,lnfg,lnkg, \
      ws_fkb,ws_bm2,ws_fvb, ws_wvT,ws_wmT, ws_wgx,ws_wgy,bg, ws_gs, ws_qs,ws_cst
  #define AT_ARGS(ROUT,POUT,SCOUT) ws_A,ws_kst,ws_vst,ws_qs,ws_cst,ws_gs,ws_fg, \
      ws_lgt,ROUT,POUT,SCOUT

  k_slotq<false><<<B_*K_,256,0,stream>>>(SQ_ARGS(ws_sl0,ws_sl0,ws_prt1,ws_psc1,ws_red1));
  k_attn<false><<<agrid,256,0,stream>>>(AT_ARGS(ws_red0,ws_prt0,ws_psc0));
  k_slotq<true><<<B_*K_,256,0,stream>>>(SQ_ARGS(ws_sl0,ws_sl1,ws_prt0,ws_psc0,ws_red0));
  k_attn<false><<<agrid,256,0,stream>>>(AT_ARGS(ws_red1,ws_prt1,ws_psc1));
  k_slotq<true><<<B_*K_,256,0,stream>>>(SQ_ARGS(ws_sl1,ws_sl0,ws_prt1,ws_psc1,ws_red1));
  k_attn<false><<<agrid,256,0,stream>>>(AT_ARGS(ws_red0,ws_prt0,ws_psc0));
  k_slotq<true><<<B_*K_,256,0,stream>>>(SQ_ARGS(ws_sl0,ws_sl1,ws_prt0,ws_psc0,ws_red0));
  k_attn<true><<<agrid,256,0,stream>>>(AT_ARGS(ws_red1,ws_prt1,ws_psc1));
  k_fin<<<dim3(NC_,B_*K_),256,0,stream>>>(ws_lgt,ws_red1,ws_fc,ws_sl1,out_slot,out_attn);
}